// Round 3
// baseline (366.182 us; speedup 1.0000x reference)
//
#include <hip/hip_runtime.h>
#include <cmath>

#define NUM_CLS 58

// ---------------- weight binarization (round-1 proven) ----------------
// w: [128][128][3][3] floats -> out: [oc][ky*3+kx][2] u64 (bit ic = sign>=0)
__global__ void prep_w3x3(const float* __restrict__ w, unsigned long long* __restrict__ out) {
    int item = blockIdx.x;            // oc*9 + k,   k = ky*3+kx
    int lane = threadIdx.x;           // 64 threads
    int oc = item / 9, k = item % 9;
    const float* base = w + (size_t)oc * 1152 + k;   // element ic at base[ic*9]
    unsigned long long b0 = __ballot(base[lane * 9] >= 0.f);
    unsigned long long b1 = __ballot(base[(lane + 64) * 9] >= 0.f);
    if (lane == 0) { out[item * 2] = b0; out[item * 2 + 1] = b1; }
}

// w: [128][128] floats -> out: [oc][2] u64
__global__ void prep_w1x1(const float* __restrict__ w, unsigned long long* __restrict__ out) {
    int oc = blockIdx.x;
    int lane = threadIdx.x;
    unsigned long long b0 = __ballot(w[oc * 128 + lane] >= 0.f);
    unsigned long long b1 = __ballot(w[oc * 128 + lane + 64] >= 0.f);
    if (lane == 0) { out[oc * 2] = b0; out[oc * 2 + 1] = b1; }
}

// ---- one block per batch element: conv0+pool -> binconv1+pool -> binconv2+pool
//      -> binconv3 -> binconv4 -> relu -> w5 -> softmax ----
__global__ __launch_bounds__(256) void fused_net(
    const float* __restrict__ x, const float* __restrict__ w0,
    const unsigned long long* __restrict__ wb1, const unsigned long long* __restrict__ wb2,
    const unsigned long long* __restrict__ wb3, const unsigned long long* __restrict__ wb4,
    const float* __restrict__ w5, float* __restrict__ out) {
    __shared__ float xs[3072];                 // input image (12 KB)
    __shared__ unsigned long long bits1[450];  // [15*15][2]
    __shared__ unsigned long long bits2[72];   // [6*6][2]
    __shared__ unsigned long long bits3[18];   // [3*3][2]
    __shared__ unsigned long long bits4[2];
    __shared__ float r_s[128];
    __shared__ float l_s[NUM_CLS];
    __shared__ float e_s[NUM_CLS];

    int b = blockIdx.x;
    int tid = threadIdx.x;

    // ================= phase 0: float conv0 + maxpool2 + sign-pack =================
    {
        const float* xb = x + (size_t)b * 3072;
        for (int i = tid; i < 3072; i += 256) xs[i] = xb[i];   // coalesced dword loads
    }
    __syncthreads();
    if (tid < 225) {                      // lane = pooled pixel
        int py = tid / 15, px = tid % 15;
        float xp[48];                     // 4x4 patch x 3 channels, in registers
#pragma unroll
        for (int c = 0; c < 3; c++)
#pragma unroll
            for (int yy = 0; yy < 4; yy++)
#pragma unroll
                for (int xx = 0; xx < 4; xx++)
                    xp[c * 16 + yy * 4 + xx] = xs[c * 1024 + (2 * py + yy) * 32 + (2 * px + xx)];
        unsigned long long b0 = 0, b1 = 0;
        for (int oc = 0; oc < 128; oc++) {
            float w[27];                  // wave-uniform -> scalar loads
#pragma unroll
            for (int j = 0; j < 27; j++) w[j] = w0[oc * 27 + j];
            float s4[4];
#pragma unroll
            for (int dy = 0; dy < 2; dy++)
#pragma unroll
                for (int dx = 0; dx < 2; dx++) {
                    float s = 0.f;
#pragma unroll
                    for (int c = 0; c < 3; c++)
#pragma unroll
                        for (int ky = 0; ky < 3; ky++)
#pragma unroll
                            for (int kx = 0; kx < 3; kx++)
                                s = fmaf(xp[c * 16 + (dy + ky) * 4 + dx + kx],
                                         w[c * 9 + ky * 3 + kx], s);
                    s4[dy * 2 + dx] = s;
                }
            bool pos = false, need = false;
#pragma unroll
            for (int i = 0; i < 4; i++) {
                if (fabsf(s4[i]) < 1e-4f) need = true;
                else pos |= (s4[i] >= 0.f);
            }
            if (__builtin_expect(need, 0)) {
                // borderline: recompute in f64 (fully unrolled, register-resident)
                double sd[4] = {0.0, 0.0, 0.0, 0.0};
#pragma unroll
                for (int dy = 0; dy < 2; dy++)
#pragma unroll
                    for (int dx = 0; dx < 2; dx++)
#pragma unroll
                        for (int c = 0; c < 3; c++)
#pragma unroll
                            for (int ky = 0; ky < 3; ky++)
#pragma unroll
                                for (int kx = 0; kx < 3; kx++)
                                    sd[dy * 2 + dx] += (double)xp[c * 16 + (dy + ky) * 4 + dx + kx] *
                                                       (double)w[c * 9 + ky * 3 + kx];
#pragma unroll
                for (int i = 0; i < 4; i++)
                    if (fabsf(s4[i]) < 1e-4f) pos |= (sd[i] >= 0.0);
            }
            unsigned long long bit = pos ? 1ull : 0ull;
            if (oc < 64) b0 |= bit << oc; else b1 |= bit << (oc - 64);
        }
        bits1[tid * 2] = b0;
        bits1[tid * 2 + 1] = b1;
    }
    __syncthreads();

    int lane = tid & 63, wave = tid >> 6, half = wave & 1, pair = wave >> 1;
    int oc = half * 64 + lane;

    // ================= phase 1: binconv1 (15->13) + maxpool2 (->6) =================
    {
        unsigned long long wr[18];
#pragma unroll
        for (int j = 0; j < 18; j++) wr[j] = wb1[oc * 18 + j];
        for (int p = pair; p < 36; p += 2) {
            int py = p / 6, px = p % 6;
            unsigned long long xp[4][4][2];
#pragma unroll
            for (int yy = 0; yy < 4; yy++)
#pragma unroll
                for (int xx = 0; xx < 4; xx++) {
                    int idx = ((2 * py + yy) * 15 + (2 * px + xx)) * 2;
                    xp[yy][xx][0] = bits1[idx];
                    xp[yy][xx][1] = bits1[idx + 1];
                }
            bool pos = false;
#pragma unroll
            for (int dy = 0; dy < 2; dy++)
#pragma unroll
                for (int dx = 0; dx < 2; dx++) {
                    int P = 0;
#pragma unroll
                    for (int ky = 0; ky < 3; ky++)
#pragma unroll
                        for (int kx = 0; kx < 3; kx++) {
                            P += __popcll(xp[dy + ky][dx + kx][0] ^ wr[(ky * 3 + kx) * 2]);
                            P += __popcll(xp[dy + ky][dx + kx][1] ^ wr[(ky * 3 + kx) * 2 + 1]);
                        }
                    pos |= (P <= 576);   // 1152 - 2P >= 0
                }
            unsigned long long m = __ballot(pos);
            if (lane == 0) bits2[p * 2 + half] = m;
        }
    }
    __syncthreads();

    // ================= phase 2: binconv2 (6->4) + maxpool(2,s1) (->3) =================
    {
        unsigned long long wr[18];
#pragma unroll
        for (int j = 0; j < 18; j++) wr[j] = wb2[oc * 18 + j];
        for (int p = pair; p < 9; p += 2) {
            int py = p / 3, px = p % 3;
            bool pos = false;
#pragma unroll
            for (int dy = 0; dy < 2; dy++)
#pragma unroll
                for (int dx = 0; dx < 2; dx++) {
                    int P = 0;
#pragma unroll
                    for (int ky = 0; ky < 3; ky++)
#pragma unroll
                        for (int kx = 0; kx < 3; kx++) {
                            int idx = ((py + dy + ky) * 6 + (px + dx + kx)) * 2;
                            P += __popcll(bits2[idx] ^ wr[(ky * 3 + kx) * 2]);
                            P += __popcll(bits2[idx + 1] ^ wr[(ky * 3 + kx) * 2 + 1]);
                        }
                    pos |= (P <= 576);
                }
            unsigned long long m = __ballot(pos);
            if (lane == 0) bits3[p * 2 + half] = m;
        }
    }
    __syncthreads();

    // ================= phase 3: binconv3 + binconv4 + relu + w5 + softmax =================
    if (tid < 128) {
        int P = 0;
#pragma unroll
        for (int k = 0; k < 9; k++) {
            P += __popcll(bits3[k * 2] ^ wb3[tid * 18 + k * 2]);
            P += __popcll(bits3[k * 2 + 1] ^ wb3[tid * 18 + k * 2 + 1]);
        }
        unsigned long long m = __ballot(P <= 576);
        if ((tid & 63) == 0) bits4[tid >> 6] = m;
    }
    __syncthreads();
    if (tid < 128) {
        unsigned long long i0 = bits4[0], i1 = bits4[1];
        int v = 128 - 2 * (int)(__popcll(i0 ^ wb4[tid * 2]) + __popcll(i1 ^ wb4[tid * 2 + 1]));
        r_s[tid] = v > 0 ? (float)v : 0.f;   // relu
    }
    __syncthreads();
    if (tid < NUM_CLS) {
        float l = 0.f;
#pragma unroll 8
        for (int k = 0; k < 128; k++) l = fmaf(w5[tid * 128 + k], r_s[k], l);
        l_s[tid] = l;
    }
    __syncthreads();
    if (tid < NUM_CLS) {
        float mx = -1e30f;
        for (int k = 0; k < NUM_CLS; k++) mx = fmaxf(mx, l_s[k]);
        e_s[tid] = expf(l_s[tid] - mx);
    }
    __syncthreads();
    if (tid < NUM_CLS) {
        float sum = 0.f;
        for (int k = 0; k < NUM_CLS; k++) sum += e_s[k];
        out[(size_t)b * NUM_CLS + tid] = e_s[tid] / sum;
    }
}

extern "C" void kernel_launch(void* const* d_in, const int* in_sizes, int n_in,
                              void* d_out, int out_size, void* d_ws, size_t ws_size,
                              hipStream_t stream) {
    const float* x  = (const float*)d_in[0];
    const float* w0 = (const float*)d_in[1];
    const float* w1 = (const float*)d_in[2];
    const float* w2 = (const float*)d_in[3];
    const float* w3 = (const float*)d_in[4];
    const float* w4 = (const float*)d_in[5];
    const float* w5 = (const float*)d_in[6];
    float* out = (float*)d_out;

    int B = in_sizes[0] / 3072;   // 1024

    size_t off = 0;
    auto carve = [&](size_t bytes) {
        void* p = (char*)d_ws + off;
        off += (bytes + 255) & ~(size_t)255;
        return p;
    };
    unsigned long long* wb1 = (unsigned long long*)carve(1152 * 2 * 8);
    unsigned long long* wb2 = (unsigned long long*)carve(1152 * 2 * 8);
    unsigned long long* wb3 = (unsigned long long*)carve(1152 * 2 * 8);
    unsigned long long* wb4 = (unsigned long long*)carve(128 * 2 * 8);
    (void)ws_size; (void)n_in; (void)out_size;

    prep_w3x3<<<1152, 64, 0, stream>>>(w1, wb1);
    prep_w3x3<<<1152, 64, 0, stream>>>(w2, wb2);
    prep_w3x3<<<1152, 64, 0, stream>>>(w3, wb3);
    prep_w1x1<<<128, 64, 0, stream>>>(w4, wb4);

    fused_net<<<B, 256, 0, stream>>>(x, w0, wb1, wb2, wb3, wb4, w5, out);
}

// Round 4
// 242.303 us; speedup vs baseline: 1.5113x; 1.5113x over previous
//
#include <hip/hip_runtime.h>
#include <cmath>

#define NUM_CLS 58

// ---------------- weight binarization (round-1 proven) ----------------
__global__ void prep_w3x3(const float* __restrict__ w, unsigned long long* __restrict__ out) {
    int item = blockIdx.x;            // oc*9 + k,   k = ky*3+kx
    int lane = threadIdx.x;           // 64 threads
    int oc = item / 9, k = item % 9;
    const float* base = w + (size_t)oc * 1152 + k;   // element ic at base[ic*9]
    unsigned long long b0 = __ballot(base[lane * 9] >= 0.f);
    unsigned long long b1 = __ballot(base[(lane + 64) * 9] >= 0.f);
    if (lane == 0) { out[item * 2] = b0; out[item * 2 + 1] = b1; }
}

__global__ void prep_w1x1(const float* __restrict__ w, unsigned long long* __restrict__ out) {
    int oc = blockIdx.x;
    int lane = threadIdx.x;
    unsigned long long b0 = __ballot(w[oc * 128 + lane] >= 0.f);
    unsigned long long b1 = __ballot(w[oc * 128 + lane + 64] >= 0.f);
    if (lane == 0) { out[oc * 2] = b0; out[oc * 2 + 1] = b1; }
}

// ---- one block per batch element: conv0+pool -> binconv1+pool -> binconv2+pool
//      -> binconv3 -> binconv4 -> relu -> w5 -> softmax ----
__global__ __launch_bounds__(256) void fused_net(
    const float* __restrict__ x, const float* __restrict__ w0,
    const unsigned long long* __restrict__ wb1, const unsigned long long* __restrict__ wb2,
    const unsigned long long* __restrict__ wb3, const unsigned long long* __restrict__ wb4,
    const float* __restrict__ w5, float* __restrict__ out) {
    __shared__ float xs[3072];                 // input image (12 KB)
    __shared__ float ws0[128 * 28];            // conv0 weights, 28-padded (14 KB)
    __shared__ unsigned long long bits1[450];  // [15*15][2]
    __shared__ unsigned long long bits2[72];   // [6*6][2]
    __shared__ unsigned long long bits3[18];   // [3*3][2]
    __shared__ unsigned long long bits4[2];
    __shared__ float r_s[128];
    __shared__ float l_s[NUM_CLS];
    __shared__ float e_s[NUM_CLS];

    int b = blockIdx.x;
    int tid = threadIdx.x;

    // ================= phase 0: float conv0 + maxpool2 + sign-pack =================
    {
        const float* xb = x + (size_t)b * 3072;
        for (int i = tid; i < 3072; i += 256) xs[i] = xb[i];       // coalesced
        for (int i = tid; i < 3456; i += 256) {                    // w0 -> LDS, padded
            int o = i / 27, j = i % 27;
            ws0[o * 28 + j] = w0[i];
        }
    }
    __syncthreads();
    if (tid < 225) {                      // thread = pooled pixel
        int py = tid / 15, px = tid % 15;
        float xp[48];                     // 4x4 patch x 3 channels, registers (loaded ONCE)
        const float2* xs2 = (const float2*)xs;
#pragma unroll
        for (int c = 0; c < 3; c++)
#pragma unroll
            for (int yy = 0; yy < 4; yy++) {
                int base2 = (c * 1024 + (2 * py + yy) * 32) / 2 + px;  // 8B-aligned b64 reads
                float2 a = xs2[base2];
                float2 q = xs2[base2 + 1];
                xp[c * 16 + yy * 4 + 0] = a.x;
                xp[c * 16 + yy * 4 + 1] = a.y;
                xp[c * 16 + yy * 4 + 2] = q.x;
                xp[c * 16 + yy * 4 + 3] = q.y;
            }
        unsigned long long b0 = 0, b1 = 0, r0 = 0, r1 = 0;
        for (int oc = 0; oc < 128; oc++) {
            // weights: wave-uniform LDS broadcast, 7x ds_read_b128
            const float4* wp = (const float4*)(ws0 + oc * 28);
            float w[28];
#pragma unroll
            for (int i = 0; i < 7; i++) {
                float4 t = wp[i];
                w[4 * i] = t.x; w[4 * i + 1] = t.y; w[4 * i + 2] = t.z; w[4 * i + 3] = t.w;
            }
            bool pos = false, need = false;
#pragma unroll
            for (int dy = 0; dy < 2; dy++)
#pragma unroll
                for (int dx = 0; dx < 2; dx++) {
                    float s = 0.f;
#pragma unroll
                    for (int c = 0; c < 3; c++)
#pragma unroll
                        for (int ky = 0; ky < 3; ky++)
#pragma unroll
                            for (int kx = 0; kx < 3; kx++)
                                s = fmaf(xp[c * 16 + (dy + ky) * 4 + dx + kx],
                                         w[c * 9 + ky * 3 + kx], s);
                    need |= (fabsf(s) < 1e-4f);
                    pos |= (s >= 0.f);
                }
            unsigned long long bit = pos ? 1ull : 0ull;
            unsigned long long nbit = need ? 1ull : 0ull;
            if (oc < 64) { b0 |= bit << oc; r0 |= nbit << oc; }
            else         { b1 |= bit << (oc - 64); r1 |= nbit << (oc - 64); }
        }
        // -------- rare cold path: redo borderline oc's in f64 --------
        if (__builtin_expect((r0 | r1) != 0ull, 0)) {
#pragma unroll
            for (int half = 0; half < 2; half++) {
                unsigned long long r = half ? r1 : r0;
                while (r) {
                    int i = __builtin_ctzll(r);
                    r &= r - 1;
                    const float* w = ws0 + (half * 64 + i) * 28;
                    bool pos = false;
#pragma unroll
                    for (int dy = 0; dy < 2; dy++)
#pragma unroll
                        for (int dx = 0; dx < 2; dx++) {
                            double sd = 0.0;
#pragma unroll
                            for (int c = 0; c < 3; c++)
#pragma unroll
                                for (int ky = 0; ky < 3; ky++)
#pragma unroll
                                    for (int kx = 0; kx < 3; kx++)
                                        sd += (double)xp[c * 16 + (dy + ky) * 4 + dx + kx] *
                                              (double)w[c * 9 + ky * 3 + kx];
                            pos |= (sd >= 0.0);
                        }
                    unsigned long long bit = pos ? 1ull : 0ull;
                    if (half) b1 = (b1 & ~(1ull << i)) | (bit << i);
                    else      b0 = (b0 & ~(1ull << i)) | (bit << i);
                }
            }
        }
        bits1[tid * 2] = b0;
        bits1[tid * 2 + 1] = b1;
    }
    __syncthreads();

    int lane = tid & 63, wave = tid >> 6, half = wave & 1, pair = wave >> 1;
    int oc = half * 64 + lane;

    // ================= phase 1: binconv1 (15->13) + maxpool2 (->6) =================
    {
        unsigned long long wr[18];
#pragma unroll
        for (int j = 0; j < 18; j++) wr[j] = wb1[oc * 18 + j];
        for (int p = pair; p < 36; p += 2) {
            int py = p / 6, px = p % 6;
            unsigned long long xp[4][4][2];
#pragma unroll
            for (int yy = 0; yy < 4; yy++)
#pragma unroll
                for (int xx = 0; xx < 4; xx++) {
                    int idx = ((2 * py + yy) * 15 + (2 * px + xx)) * 2;
                    xp[yy][xx][0] = bits1[idx];
                    xp[yy][xx][1] = bits1[idx + 1];
                }
            bool pos = false;
#pragma unroll
            for (int dy = 0; dy < 2; dy++)
#pragma unroll
                for (int dx = 0; dx < 2; dx++) {
                    int P = 0;
#pragma unroll
                    for (int ky = 0; ky < 3; ky++)
#pragma unroll
                        for (int kx = 0; kx < 3; kx++) {
                            P += __popcll(xp[dy + ky][dx + kx][0] ^ wr[(ky * 3 + kx) * 2]);
                            P += __popcll(xp[dy + ky][dx + kx][1] ^ wr[(ky * 3 + kx) * 2 + 1]);
                        }
                    pos |= (P <= 576);   // 1152 - 2P >= 0
                }
            unsigned long long m = __ballot(pos);
            if (lane == 0) bits2[p * 2 + half] = m;
        }
    }
    __syncthreads();

    // ================= phase 2: binconv2 (6->4) + maxpool(2,s1) (->3) =================
    {
        unsigned long long wr[18];
#pragma unroll
        for (int j = 0; j < 18; j++) wr[j] = wb2[oc * 18 + j];
        for (int p = pair; p < 9; p += 2) {
            int py = p / 3, px = p % 3;
            bool pos = false;
#pragma unroll
            for (int dy = 0; dy < 2; dy++)
#pragma unroll
                for (int dx = 0; dx < 2; dx++) {
                    int P = 0;
#pragma unroll
                    for (int ky = 0; ky < 3; ky++)
#pragma unroll
                        for (int kx = 0; kx < 3; kx++) {
                            int idx = ((py + dy + ky) * 6 + (px + dx + kx)) * 2;
                            P += __popcll(bits2[idx] ^ wr[(ky * 3 + kx) * 2]);
                            P += __popcll(bits2[idx + 1] ^ wr[(ky * 3 + kx) * 2 + 1]);
                        }
                    pos |= (P <= 576);
                }
            unsigned long long m = __ballot(pos);
            if (lane == 0) bits3[p * 2 + half] = m;
        }
    }
    __syncthreads();

    // ================= phase 3: binconv3 + binconv4 + relu + w5 + softmax =================
    if (tid < 128) {
        int P = 0;
#pragma unroll
        for (int k = 0; k < 9; k++) {
            P += __popcll(bits3[k * 2] ^ wb3[tid * 18 + k * 2]);
            P += __popcll(bits3[k * 2 + 1] ^ wb3[tid * 18 + k * 2 + 1]);
        }
        unsigned long long m = __ballot(P <= 576);
        if ((tid & 63) == 0) bits4[tid >> 6] = m;
    }
    __syncthreads();
    if (tid < 128) {
        unsigned long long i0 = bits4[0], i1 = bits4[1];
        int v = 128 - 2 * (int)(__popcll(i0 ^ wb4[tid * 2]) + __popcll(i1 ^ wb4[tid * 2 + 1]));
        r_s[tid] = v > 0 ? (float)v : 0.f;   // relu
    }
    __syncthreads();
    if (tid < NUM_CLS) {
        float l = 0.f;
#pragma unroll 8
        for (int k = 0; k < 128; k++) l = fmaf(w5[tid * 128 + k], r_s[k], l);
        l_s[tid] = l;
    }
    __syncthreads();
    if (tid < NUM_CLS) {
        float mx = -1e30f;
        for (int k = 0; k < NUM_CLS; k++) mx = fmaxf(mx, l_s[k]);
        e_s[tid] = expf(l_s[tid] - mx);
    }
    __syncthreads();
    if (tid < NUM_CLS) {
        float sum = 0.f;
        for (int k = 0; k < NUM_CLS; k++) sum += e_s[k];
        out[(size_t)b * NUM_CLS + tid] = e_s[tid] / sum;
    }
}

extern "C" void kernel_launch(void* const* d_in, const int* in_sizes, int n_in,
                              void* d_out, int out_size, void* d_ws, size_t ws_size,
                              hipStream_t stream) {
    const float* x  = (const float*)d_in[0];
    const float* w0 = (const float*)d_in[1];
    const float* w1 = (const float*)d_in[2];
    const float* w2 = (const float*)d_in[3];
    const float* w3 = (const float*)d_in[4];
    const float* w4 = (const float*)d_in[5];
    const float* w5 = (const float*)d_in[6];
    float* out = (float*)d_out;

    int B = in_sizes[0] / 3072;   // 1024

    size_t off = 0;
    auto carve = [&](size_t bytes) {
        void* p = (char*)d_ws + off;
        off += (bytes + 255) & ~(size_t)255;
        return p;
    };
    unsigned long long* wb1 = (unsigned long long*)carve(1152 * 2 * 8);
    unsigned long long* wb2 = (unsigned long long*)carve(1152 * 2 * 8);
    unsigned long long* wb3 = (unsigned long long*)carve(1152 * 2 * 8);
    unsigned long long* wb4 = (unsigned long long*)carve(128 * 2 * 8);
    (void)ws_size; (void)n_in; (void)out_size;

    prep_w3x3<<<1152, 64, 0, stream>>>(w1, wb1);
    prep_w3x3<<<1152, 64, 0, stream>>>(w2, wb2);
    prep_w3x3<<<1152, 64, 0, stream>>>(w3, wb3);
    prep_w1x1<<<128, 64, 0, stream>>>(w4, wb4);

    fused_net<<<B, 256, 0, stream>>>(x, w0, wb1, wb2, wb3, wb4, w5, out);
}